// Round 7
// baseline (128.115 us; speedup 1.0000x reference)
//
#include <hip/hip_runtime.h>
#include <hip/hip_cooperative_groups.h>

namespace cg = cooperative_groups;

// ---------------- problem constants ----------------
#define NBLK   98304     // 8*3*64*64 total 8x8 blocks
#define NPB    12288     // blocks per batch (3*64*64)
#define HW     512
#define NUMBITS 4096
#define RANK0  29490     // floor(0.3*(NBLK-1))
#define RANK1  29491
#define STEGO_N 6291456  // 8*3*512*512
#define ELIG   111       // ceil(4096/37) blocks contain eligible coefficients
#define HIST   8192      // fixed bins over variance range [0, 0.25]
#define CCAP   2048

typedef unsigned long long ull;

// ---------------- DCT matrix as compile-time constants ----------------
struct DTab { double d[8][8]; };

constexpr double CT_[9] = {
  1.0,
  0.98078528040323044913,
  0.92387953251128675613,
  0.83146961230254523708,
  0.70710678118654752440,
  0.55557023301960222474,
  0.38268343236508977173,
  0.19509032201612826785,
  0.0
};
constexpr double cospi16(int m){           // cos(pi*m/16), m >= 0
  int r = m % 32;
  return (r<=8) ? CT_[r] : (r<=16) ? -CT_[16-r] : (r<=24) ? -CT_[r-16] : CT_[32-r];
}
constexpr DTab make_dtab(){
  DTab t{};
  for(int k=0;k<8;k++) for(int n=0;n<8;n++){
    double s = (k==0) ? 0.35355339059327376220 : 0.5; // sqrt(1/8), sqrt(2/8)
    t.d[k][n] = s * cospi16((2*n+1)*k);
  }
  return t;
}
constexpr DTab DT = make_dtab();

constexpr ull make_fmask(){ // bit u*8+v set iff 3 <= u+v <= 8
  ull m = 0;
  for(int u=0;u<8;u++) for(int v=0;v<8;v++){
    int s=u+v; if(s>=3 && s<=8) m |= (1ULL << (u*8+v));
  }
  return m;
}
constexpr ull FMASK = make_fmask();  // 37 bits set

__device__ __forceinline__ int binof(double v){
  int b = (int)(v * 32768.0);               // HIST/0.25 — fixed, deterministic
  if(b > HIST-1) b = HIST-1;
  return b;                                 // v >= 0 always
}

// copy block i to out, zero its map, return fp64 variance
__device__ __forceinline__ double stats_body(const float* __restrict__ cover,
    float* __restrict__ out, int i){
  int m = i & 63, n = (i>>6)&63, bc = i>>12;
  const float* p  = cover + ((size_t)bc*HW + (size_t)n*8)*HW + (size_t)m*8;
  float*       po = out   + ((size_t)bc*HW + (size_t)n*8)*HW + (size_t)m*8;
  double s1=0.0, s2=0.0;
#pragma unroll
  for(int r=0;r<8;r++){
    const float4* q = (const float4*)(p + (size_t)r*HW);
    float4 a = q[0], b = q[1];
    float4* w = (float4*)(po + (size_t)r*HW);
    w[0]=a; w[1]=b;
    double x;
    x=(double)a.x; s1+=x; s2+=x*x;
    x=(double)a.y; s1+=x; s2+=x*x;
    x=(double)a.z; s1+=x; s2+=x*x;
    x=(double)a.w; s1+=x; s2+=x*x;
    x=(double)b.x; s1+=x; s2+=x*x;
    x=(double)b.y; s1+=x; s2+=x*x;
    x=(double)b.z; s1+=x; s2+=x*x;
    x=(double)b.w; s1+=x; s2+=x*x;
  }
  double mean = s1*(1.0/64.0);
  double v = s2*(1.0/64.0) - mean*mean;
  if(v < 0.0) v = 0.0;
  float4 z = make_float4(0.f,0.f,0.f,0.f);
  float4* pm = (float4*)(out + (size_t)STEGO_N + (size_t)i*64);
#pragma unroll
  for(int j=0;j<16;j++) pm[j] = z;
  return v;
}

// wave-shuffle fp64 DCT embed of queue[0..nq) with 16 waves (tid in [0,1024))
__device__ __forceinline__ void embed_blocks(const float* __restrict__ cover,
    const int* __restrict__ secret, float* __restrict__ out,
    const int* queue, int nq, int tid){
  int wid = tid>>6, lane = tid&63;
  int lr = lane>>3, lc = lane&7;
  for(int q = wid; q < nq; q += 16){
    int bi = queue[q], S2 = q;
    int m = bi & 63, n = (bi>>6)&63, bc = bi>>12, bb = bi / NPB;
    const float* p  = cover + ((size_t)bc*HW + (size_t)n*8)*HW + (size_t)m*8;
    float*       po = out   + ((size_t)bc*HW + (size_t)n*8)*HW + (size_t)m*8;
    double x = (double)p[(size_t)lr*HW + lc];     // X[lr][lc]
    // stage1: T1[r][v] = sum_j X[r][j]*D[v][j]
    double t1 = 0.0;
#pragma unroll
    for(int j=0;j<8;j++) t1 += __shfl(x, lr*8+j) * DT.d[lc][j];
    // stage2: C[u][v] = sum_k D[u][k]*T1[k][v]
    double coef = 0.0;
#pragma unroll
    for(int k=0;k<8;k++) coef += DT.d[lr][k] * __shfl(t1, k*8+lc);
    // embedding
    bool sel = (FMASK>>lane)&1ULL;
    float mv = 0.f;
    if(sel){
      int fp  = (int)__popcll(FMASK & ((1ULL<<lane)-1ULL));
      int ord = 37*S2 + fp;
      if(ord < NUMBITS){
        mv = 1.f;
        double rnd = rint(coef);                  // round half-to-even == jnp.round
        int lsb = ((int)fabs(rnd)) & 1;
        int bit = secret[(size_t)bb*NUMBITS + ord];
        if(lsb != bit) coef += ((coef>=0.0)?1.0:-1.0)*(2.0*(double)bit-1.0)*0.5;
      }
    }
    out[(size_t)STEGO_N + (size_t)bi*64 + lane] = mv;
    // inv stage1: T2[r][v] = sum_u D[u][r]*M[u][v]
    double t2 = 0.0;
#pragma unroll
    for(int u=0;u<8;u++) t2 += DT.d[u][lr] * __shfl(coef, u*8+lc);
    // inv stage2: pix[r][k] = sum_q T2[r][q]*D[q][k]
    double px = 0.0;
#pragma unroll
    for(int qq=0;qq<8;qq++) px += __shfl(t2, lr*8+qq) * DT.d[qq][lc];
    po[(size_t)lr*HW + lc] = (float)px;
  }
}

// ================= cooperative single-dispatch kernel =================
// 96 WGs x 1024 threads = 98304 threads, one per 8x8 block.
__global__ __launch_bounds__(1024) void k_all(const float* __restrict__ cover,
    const int* __restrict__ secret, float* __restrict__ out,
    double* __restrict__ var, unsigned* __restrict__ bins,
    unsigned* __restrict__ cand_cnt, ull* __restrict__ cand){
  cg::grid_group grid = cg::this_grid();
  __shared__ ull scand[CCAP];               // 16 KB
  __shared__ unsigned wsum[16];
  __shared__ int sdesc[3];                  // b0, b1, Cb
  __shared__ double sAB[2];
  __shared__ int queue[ELIG];
  __shared__ unsigned wcnt[16];
  int tid = threadIdx.x;
  int wg  = blockIdx.x;
  int i   = wg*1024 + tid;
  int lane = tid & 63, wid = tid >> 6;

  // ---- P0: copy + map-zero + variance (v stays in register) + zero scratch ----
  if(i < HIST) bins[i] = 0u;
  if(i == HIST) *cand_cnt = 0u;
  double v = stats_body(cover, out, i);
  var[i] = v;
  grid.sync();

  // ---- P1: global histogram, one atomic per thread ----
  atomicAdd(&bins[binof(v)], 1u);
  grid.sync();

  // ---- P2: locate rank bins (every WG, redundant & deterministic) + gather ----
  {
    int base = tid*8;
    unsigned bl[8]; unsigned part = 0;
#pragma unroll
    for(int k=0;k<8;k++){ bl[k]=bins[base+k]; part += bl[k]; }
    unsigned incl = part;
#pragma unroll
    for(int off=1; off<64; off<<=1){
      unsigned t = __shfl_up(incl, off);
      if(lane >= off) incl += t;
    }
    if(lane==63) wsum[wid]=incl;
    __syncthreads();
    unsigned wpre=0;
#pragma unroll
    for(int w=0;w<16;w++) if(w<wid) wpre += wsum[w];
    unsigned excl = wpre + incl - part;
    unsigned c = excl;
#pragma unroll
    for(int k=0;k<8;k++){
      if((unsigned)RANK0 >= c && (unsigned)RANK0 < c+bl[k]){ sdesc[0]=base+k; sdesc[2]=(int)c; }
      if((unsigned)RANK1 >= c && (unsigned)RANK1 < c+bl[k]){ sdesc[1]=base+k; }
      c += bl[k];
    }
    __syncthreads();
    int b0=sdesc[0], b1=sdesc[1];
    int bn = binof(v);
    if(bn >= b0 && bn <= b1){
      unsigned idx = atomicAdd(cand_cnt, 1u);
      if(idx < CCAP) cand[idx] = (ull)__double_as_longlong(v);
    }
  }
  grid.sync();

  // ---- P3: WG0 only: rank-select -> thr -> ballot queue -> embed ----
  if(wg != 0) return;
  unsigned Ku = *cand_cnt;
  int K = (Ku < (unsigned)CCAP) ? (int)Ku : CCAP;
  for(int t=tid; t<K; t+=1024) scand[t] = cand[t];
  __syncthreads();
  if(wid == 0){
    int r0 = RANK0 - sdesc[2], r1 = RANK1 - sdesc[2];
    for(int t=lane; t<K; t+=64){
      ull x = scand[t];
      int cl=0, ce=0;
      for(int j=0;j<K;j++){ ull y=scand[j]; cl += (y<x); ce += (y==x); }
      if(cl<=r0 && r0<cl+ce) sAB[0]=__longlong_as_double((long long)x);
      if(cl<=r1 && r1<cl+ce) sAB[1]=__longlong_as_double((long long)x);
    }
  }
  __syncthreads();
  double A=sAB[0], Bv=sAB[1];
  double thr = A + 0.9*(Bv - A);   // selection: var_norm>thr <=> var>thr_raw

  // chunked ballot scan in index order; stop once ELIG blocks queued
  int total = 0;
  for(int chunk=0; chunk<96; chunk++){
    int ii = chunk*1024 + tid;
    int f = (var[ii] > thr) ? 1 : 0;
    ull bal = __ballot(f);
    if(lane==0) wcnt[wid] = (unsigned)__popcll(bal);
    __syncthreads();
    int wpre=0, csum=0;
#pragma unroll
    for(int w=0;w<16;w++){
      int cc = (int)wcnt[w];
      if(w<wid) wpre += cc;
      csum += cc;
    }
    int P = total + wpre + (int)__popcll(bal & ((1ULL<<lane)-1ULL));
    if(f && P < ELIG) queue[P] = ii;
    total += csum;
    __syncthreads();
    if(total >= ELIG) break;
  }
  int nq = (total < ELIG) ? total : ELIG;
  embed_blocks(cover, secret, out, queue, nq, tid);
}

// ================= fallback (R6 pipeline, correctness-proven) =================

__global__ __launch_bounds__(256) void k_stats(const float* __restrict__ cover,
    float* __restrict__ out, double* __restrict__ var,
    unsigned* __restrict__ bins, unsigned* __restrict__ cand_cnt){
  int i = blockIdx.x*256 + threadIdx.x;
  if(i < HIST) bins[i] = 0u;
  if(i == HIST) *cand_cnt = 0u;
  var[i] = stats_body(cover, out, i);
}

__global__ __launch_bounds__(1024) void k_hist(const double* __restrict__ var,
    unsigned* __restrict__ bins){
  int i = blockIdx.x*1024 + threadIdx.x;
  atomicAdd(&bins[binof(var[i])], 1u);
}

__global__ __launch_bounds__(1024) void k_gather(const double* __restrict__ var,
    const unsigned* __restrict__ bins, unsigned* __restrict__ cand_cnt,
    ull* __restrict__ cand, int* __restrict__ desc){
  __shared__ unsigned sscan[1024];
  __shared__ int sdesc[3];
  int tid = threadIdx.x;
  int base = tid*8;
  unsigned bl[8];
  unsigned ls = 0;
#pragma unroll
  for(int k=0;k<8;k++){ bl[k]=bins[base+k]; ls += bl[k]; }
  sscan[tid]=ls; __syncthreads();
  for(int off=1;off<1024;off<<=1){
    unsigned add = (tid>=off)? sscan[tid-off] : 0u;
    __syncthreads();
    sscan[tid]+=add;
    __syncthreads();
  }
  unsigned incl = sscan[tid], excl = incl - ls;
  unsigned c = excl;
#pragma unroll
  for(int k=0;k<8;k++){
    if((unsigned)RANK0 >= c && (unsigned)RANK0 < c+bl[k]){ sdesc[0]=base+k; sdesc[2]=(int)c; }
    if((unsigned)RANK1 >= c && (unsigned)RANK1 < c+bl[k]){ sdesc[1]=base+k; }
    c += bl[k];
  }
  __syncthreads();
  int b0=sdesc[0], b1=sdesc[1];
  if(blockIdx.x==0 && tid==0){ desc[0]=b0; desc[1]=b1; desc[2]=sdesc[2]; }
  int i = blockIdx.x*1024 + tid;
  double v = var[i];
  int bn = binof(v);
  if(bn >= b0 && bn <= b1){
    unsigned idx = atomicAdd(cand_cnt, 1u);
    if(idx < CCAP) cand[idx] = (ull)__double_as_longlong(v);
  }
}

__global__ __launch_bounds__(1024) void k_final(const float* __restrict__ cover,
    const int* __restrict__ secret, const double* __restrict__ var,
    const int* __restrict__ desc, const unsigned* __restrict__ cand_cnt,
    const ull* __restrict__ gcand, float* __restrict__ out){
  __shared__ ull scand[CCAP];
  __shared__ int queue[ELIG];
  __shared__ unsigned wcnt[16];
  __shared__ double sAB[2];
  int tid = threadIdx.x;
  int lane = tid & 63, wid = tid >> 6;
  unsigned Ku = *cand_cnt;
  int K = (Ku < (unsigned)CCAP) ? (int)Ku : CCAP;
  for(int t=tid;t<K;t+=1024) scand[t]=gcand[t];
  int Cb = desc[2];
  __syncthreads();
  if(wid==0){
    int r0 = RANK0 - Cb, r1 = RANK1 - Cb;
    for(int t=lane; t<K; t+=64){
      ull x = scand[t];
      int cl=0, ce=0;
      for(int j=0;j<K;j++){ ull y=scand[j]; cl += (y<x); ce += (y==x); }
      if(cl<=r0 && r0<cl+ce) sAB[0]=__longlong_as_double((long long)x);
      if(cl<=r1 && r1<cl+ce) sAB[1]=__longlong_as_double((long long)x);
    }
  }
  __syncthreads();
  double A=sAB[0], Bv=sAB[1];
  double thr = A + 0.9*(Bv - A);

  int total = 0;
  for(int chunk=0; chunk<96; chunk++){
    int ii = chunk*1024 + tid;
    int f = (var[ii] > thr) ? 1 : 0;
    ull bal = __ballot(f);
    if(lane==0) wcnt[wid] = (unsigned)__popcll(bal);
    __syncthreads();
    int wpre=0, csum=0;
#pragma unroll
    for(int w=0;w<16;w++){
      int cc = (int)wcnt[w];
      if(w<wid) wpre += cc;
      csum += cc;
    }
    int P = total + wpre + (int)__popcll(bal & ((1ULL<<lane)-1ULL));
    if(f && P < ELIG) queue[P] = ii;
    total += csum;
    __syncthreads();
    if(total >= ELIG) break;
  }
  int nq = (total < ELIG) ? total : ELIG;
  embed_blocks(cover, secret, out, queue, nq, tid);
}

// ---------------- host launch ----------------
extern "C" void kernel_launch(void* const* d_in, const int* in_sizes, int n_in,
                              void* d_out, int out_size, void* d_ws, size_t ws_size,
                              hipStream_t stream) {
  const float* cover  = (const float*)d_in[0];
  const int*   secret = (const int*)d_in[1];
  float* out = (float*)d_out;
  char*  ws  = (char*)d_ws;

  // ws layout (bytes)
  double*   var      = (double*)(ws);             // 98304*8 = 786432
  unsigned* bins     = (unsigned*)(ws + 786432);  // 8192*4  -> 819200
  unsigned* cand_cnt = (unsigned*)(ws + 819200);  // 4 (pad)  -> 819208
  int*      desc     = (int*)(ws + 819208);       // 3 ints (pad to 24) -> 819232
  ull*      cand     = (ull*)(ws + 819232);       // 2048*8  -> 835616

  void* args[7] = { (void*)&cover, (void*)&secret, (void*)&out,
                    (void*)&var, (void*)&bins, (void*)&cand_cnt, (void*)&cand };
  hipError_t e = hipLaunchCooperativeKernel((const void*)k_all, dim3(96), dim3(1024),
                                            args, 0, stream);
  if(e != hipSuccess){
    // fallback: proven 4-kernel pipeline
    k_stats <<<NBLK/256,  256,  0, stream>>>(cover, out, var, bins, cand_cnt);
    k_hist  <<<NBLK/1024, 1024, 0, stream>>>(var, bins);
    k_gather<<<NBLK/1024, 1024, 0, stream>>>(var, bins, cand_cnt, cand, desc);
    k_final <<<1,         1024, 0, stream>>>(cover, secret, var, desc, cand_cnt, cand, out);
  }
}

// Round 8
// 65.627 us; speedup vs baseline: 1.9522x; 1.9522x over previous
//
#include <hip/hip_runtime.h>

// ---------------- problem constants ----------------
#define NBLK   98304     // 8*3*64*64 total 8x8 blocks
#define NPB    12288     // blocks per batch (3*64*64)
#define HW     512
#define NUMBITS 4096
#define RANK0  29490     // floor(0.3*(NBLK-1))
#define RANK1  29491
#define STEGO_N 6291456  // 8*3*512*512
#define ELIG   111       // ceil(4096/37) blocks contain eligible coefficients
#define HIST   8192      // fixed bins over variance range [0, 0.25]
#define CCAP   2048

typedef unsigned long long ull;

// ---------------- DCT matrix as compile-time constants ----------------
struct DTab { double d[8][8]; };

constexpr double CT_[9] = {
  1.0,
  0.98078528040323044913,
  0.92387953251128675613,
  0.83146961230254523708,
  0.70710678118654752440,
  0.55557023301960222474,
  0.38268343236508977173,
  0.19509032201612826785,
  0.0
};
constexpr double cospi16(int m){           // cos(pi*m/16), m >= 0
  int r = m % 32;
  return (r<=8) ? CT_[r] : (r<=16) ? -CT_[16-r] : (r<=24) ? -CT_[r-16] : CT_[32-r];
}
constexpr DTab make_dtab(){
  DTab t{};
  for(int k=0;k<8;k++) for(int n=0;n<8;n++){
    double s = (k==0) ? 0.35355339059327376220 : 0.5; // sqrt(1/8), sqrt(2/8)
    t.d[k][n] = s * cospi16((2*n+1)*k);
  }
  return t;
}
constexpr DTab DT = make_dtab();

constexpr ull make_fmask(){ // bit u*8+v set iff 3 <= u+v <= 8
  ull m = 0;
  for(int u=0;u<8;u++) for(int v=0;v<8;v++){
    int s=u+v; if(s>=3 && s<=8) m |= (1ULL << (u*8+v));
  }
  return m;
}
constexpr ull FMASK = make_fmask();  // 37 bits set

__device__ __forceinline__ int binof(double v){
  int b = (int)(v * 32768.0);               // HIST/0.25 — fixed, deterministic
  if(b > HIST-1) b = HIST-1;
  return b;                                 // v >= 0 always
}

// ---------------- kernels ----------------

// zero bins + candidate counter (own kernel: hipMemsetAsync fill costs 42us)
__global__ __launch_bounds__(1024) void k_zero(unsigned* __restrict__ bins,
    unsigned* __restrict__ cand_cnt){
  int i = blockIdx.x*1024 + threadIdx.x;
  if(i < HIST) bins[i] = 0u;
  if(i == 0) *cand_cnt = 0u;
}

// fused: stego = cover (copy), map = 0, fp64 variance, LDS histogram + merge
__global__ __launch_bounds__(256) void k_stats(const float* __restrict__ cover,
    float* __restrict__ out, double* __restrict__ var,
    unsigned* __restrict__ bins){
  __shared__ unsigned h[HIST];              // 32 KB
  int tid = threadIdx.x;
  int i = blockIdx.x*256 + tid;             // block id over (b,c,n,m)
  for(int j=tid;j<HIST;j+=256) h[j]=0u;
  int m = i & 63, n = (i>>6)&63, bc = i>>12;
  const float* p  = cover + ((size_t)bc*HW + (size_t)n*8)*HW + (size_t)m*8;
  float*       po = out   + ((size_t)bc*HW + (size_t)n*8)*HW + (size_t)m*8;
  double s1=0.0, s2=0.0;
#pragma unroll
  for(int r=0;r<8;r++){
    const float4* q = (const float4*)(p + (size_t)r*HW);
    float4 a = q[0], b = q[1];
    float4* w = (float4*)(po + (size_t)r*HW);
    w[0]=a; w[1]=b;
    double x;
    x=(double)a.x; s1+=x; s2+=x*x;
    x=(double)a.y; s1+=x; s2+=x*x;
    x=(double)a.z; s1+=x; s2+=x*x;
    x=(double)a.w; s1+=x; s2+=x*x;
    x=(double)b.x; s1+=x; s2+=x*x;
    x=(double)b.y; s1+=x; s2+=x*x;
    x=(double)b.z; s1+=x; s2+=x*x;
    x=(double)b.w; s1+=x; s2+=x*x;
  }
  double mean = s1*(1.0/64.0);
  double v = s2*(1.0/64.0) - mean*mean;
  if(v < 0.0) v = 0.0;
  var[i] = v;
  // zero this block's embedding map (fixed up later for eligible blocks)
  float4 z = make_float4(0.f,0.f,0.f,0.f);
  float4* pm = (float4*)(out + (size_t)STEGO_N + (size_t)i*64);
#pragma unroll
  for(int j=0;j<16;j++) pm[j] = z;
  // LDS histogram + sparse global merge
  __syncthreads();
  atomicAdd(&h[binof(v)], 1u);
  __syncthreads();
  for(int j=tid;j<HIST;j+=256){
    unsigned c = h[j];
    if(c) atomicAdd(&bins[j], c);
  }
}

// every WG redundantly locates the bins holding RANK0/RANK1 (+ count below b0)
// via a wave-shfl scan; then gathers its own slice's candidates. WG0 -> desc.
__global__ __launch_bounds__(1024) void k_gather(const double* __restrict__ var,
    const unsigned* __restrict__ bins, unsigned* __restrict__ cand_cnt,
    ull* __restrict__ cand, int* __restrict__ desc){
  __shared__ unsigned wsum[16];
  __shared__ int sdesc[3];                  // b0, b1, Cb (count below b0)
  int tid = threadIdx.x;
  int lane = tid & 63, wid = tid >> 6;
  int base = tid*8;
  unsigned bl[8]; unsigned part = 0;
#pragma unroll
  for(int k=0;k<8;k++){ bl[k]=bins[base+k]; part += bl[k]; }
  unsigned incl = part;
#pragma unroll
  for(int off=1; off<64; off<<=1){
    unsigned t = __shfl_up(incl, off);
    if(lane >= off) incl += t;
  }
  if(lane==63) wsum[wid]=incl;
  __syncthreads();
  unsigned wpre=0;
#pragma unroll
  for(int w=0;w<16;w++) if(w<wid) wpre += wsum[w];
  unsigned c = wpre + incl - part;          // exclusive prefix of this thread's 8 bins
#pragma unroll
  for(int k=0;k<8;k++){
    if((unsigned)RANK0 >= c && (unsigned)RANK0 < c+bl[k]){ sdesc[0]=base+k; sdesc[2]=(int)c; }
    if((unsigned)RANK1 >= c && (unsigned)RANK1 < c+bl[k]){ sdesc[1]=base+k; }
    c += bl[k];
  }
  __syncthreads();
  int b0=sdesc[0], b1=sdesc[1];
  if(blockIdx.x==0 && tid==0){ desc[0]=b0; desc[1]=b1; desc[2]=sdesc[2]; }
  // gather candidates from this WG's slice
  int i = blockIdx.x*1024 + tid;
  double v = var[i];
  int bn = binof(v);
  if(bn >= b0 && bn <= b1){
    unsigned idx = atomicAdd(cand_cnt, 1u);
    if(idx < CCAP) cand[idx] = (ull)__double_as_longlong(v);
  }
}

// every WG redundantly rank-selects s[RANK0], s[RANK1] from the candidates
// -> thr; texture flags via ballot; write packed (flag|localrank) + WG counts
__global__ __launch_bounds__(1024) void k_tex(const double* __restrict__ var,
    const int* __restrict__ desc, const unsigned* __restrict__ cand_cnt,
    const ull* __restrict__ gcand, int* __restrict__ packedP,
    int* __restrict__ bsums){
  __shared__ ull scand[CCAP];               // 16 KB
  __shared__ unsigned wcnt[16];
  __shared__ double sAB[2];
  int tid = threadIdx.x;
  int lane = tid & 63, wid = tid >> 6;
  unsigned Ku = *cand_cnt;
  int K = (Ku < (unsigned)CCAP) ? (int)Ku : CCAP;
  for(int t=tid;t<K;t+=1024) scand[t]=gcand[t];
  int Cb = desc[2];
  __syncthreads();
  int r0 = RANK0 - Cb, r1 = RANK1 - Cb;
  for(int t=tid; t<K; t+=1024){
    ull x = scand[t];
    int cl=0, ce=0;
    for(int j=0;j<K;j++){ ull y=scand[j]; cl += (y<x); ce += (y==x); }
    if(cl<=r0 && r0<cl+ce) sAB[0]=__longlong_as_double((long long)x);
    if(cl<=r1 && r1<cl+ce) sAB[1]=__longlong_as_double((long long)x);
  }
  __syncthreads();
  double A=sAB[0], Bv=sAB[1];
  double thr = A + 0.9*(Bv - A);   // selection: var_norm>thr <=> var>thr_raw
  int i = blockIdx.x*1024 + tid;
  int f = (var[i] > thr) ? 1 : 0;
  ull bal = __ballot(f);
  if(lane==0) wcnt[wid] = (unsigned)__popcll(bal);
  __syncthreads();
  int wpre=0, csum=0;
#pragma unroll
  for(int w=0;w<16;w++){
    int cc = (int)wcnt[w];
    if(w<wid) wpre += cc;
    csum += cc;
  }
  int P = wpre + (int)__popcll(bal & ((1ULL<<lane)-1ULL));  // local selected-rank
  packedP[i] = (int)((f ? 0x80000000u : 0u) | (unsigned)P);
  if(tid==0) bsums[blockIdx.x] = csum;
}

// WG g: base = sum bsums[0..g); early-exit if base>=ELIG; queue own eligible
// blocks; 16-wave shuffle-DCT fp64 embed
__global__ __launch_bounds__(1024) void k_embed(const float* __restrict__ cover,
    const int* __restrict__ secret, const int* __restrict__ packedP,
    const int* __restrict__ bsums, float* __restrict__ out){
  __shared__ int sb[128];
  __shared__ int qi[128], qs[128];
  __shared__ int qcnt;
  int tid = threadIdx.x;
  int g = blockIdx.x;
  if(tid==0) qcnt = 0;
  if(tid < 128) sb[tid] = (tid < g && tid < 96) ? bsums[tid] : 0;
  __syncthreads();
  if(tid < 64) sb[tid] += sb[tid+64];
  __syncthreads();
  if(tid < 32) sb[tid] += sb[tid+32];
  __syncthreads();
  if(tid < 16) sb[tid] += sb[tid+16];
  __syncthreads();
  if(tid < 8) sb[tid] += sb[tid+8];
  __syncthreads();
  if(tid < 4) sb[tid] += sb[tid+4];
  __syncthreads();
  if(tid < 2) sb[tid] += sb[tid+2];
  __syncthreads();
  int base = sb[0] + sb[1];                 // # selected blocks before this WG
  if(base >= ELIG) return;                  // uniform: no eligible block here
  int i = g*1024 + tid;
  unsigned pp = (unsigned)packedP[i];
  int f = (int)(pp>>31);
  int P = (int)(pp & 0x7FFFFFFFu);
  int S = base + P;                         // global selected-rank of block i
  if(f && S < ELIG){
    int q = atomicAdd(&qcnt, 1);
    qi[q]=i; qs[q]=S;
  }
  __syncthreads();
  int nq = qcnt;
  if(nq == 0) return;

  // wave-parallel embed: lane l owns coefficient/pixel (l>>3, l&7); fp64 shuffles
  int wid = tid >> 6, lane = tid & 63;
  int lr = lane>>3, lc = lane&7;
  for(int q = wid; q < nq; q += 16){
    int bi = qi[q], S2 = qs[q];
    int m = bi & 63, n = (bi>>6)&63, bc = bi>>12, bb = bi / NPB;
    const float* p  = cover + ((size_t)bc*HW + (size_t)n*8)*HW + (size_t)m*8;
    float*       po = out   + ((size_t)bc*HW + (size_t)n*8)*HW + (size_t)m*8;
    double x = (double)p[(size_t)lr*HW + lc];     // X[lr][lc]
    // stage1: T1[r][v] = sum_j X[r][j]*D[v][j]
    double t1 = 0.0;
#pragma unroll
    for(int j=0;j<8;j++) t1 += __shfl(x, lr*8+j) * DT.d[lc][j];
    // stage2: C[u][v] = sum_k D[u][k]*T1[k][v]
    double coef = 0.0;
#pragma unroll
    for(int k=0;k<8;k++) coef += DT.d[lr][k] * __shfl(t1, k*8+lc);
    // embedding
    bool sel = (FMASK>>lane)&1ULL;
    float mv = 0.f;
    if(sel){
      int fp  = (int)__popcll(FMASK & ((1ULL<<lane)-1ULL));
      int ord = 37*S2 + fp;
      if(ord < NUMBITS){
        mv = 1.f;
        double rnd = rint(coef);                  // round half-to-even == jnp.round
        int lsb = ((int)fabs(rnd)) & 1;
        int bit = secret[(size_t)bb*NUMBITS + ord];
        if(lsb != bit) coef += ((coef>=0.0)?1.0:-1.0)*(2.0*(double)bit-1.0)*0.5;
      }
    }
    out[(size_t)STEGO_N + (size_t)bi*64 + lane] = mv;
    // inv stage1: T2[r][v] = sum_u D[u][r]*M[u][v]
    double t2 = 0.0;
#pragma unroll
    for(int u=0;u<8;u++) t2 += DT.d[u][lr] * __shfl(coef, u*8+lc);
    // inv stage2: pix[r][k] = sum_q T2[r][q]*D[q][k]
    double px = 0.0;
#pragma unroll
    for(int qq=0;qq<8;qq++) px += __shfl(t2, lr*8+qq) * DT.d[qq][lc];
    po[(size_t)lr*HW + lc] = (float)px;
  }
}

// ---------------- host launch ----------------
extern "C" void kernel_launch(void* const* d_in, const int* in_sizes, int n_in,
                              void* d_out, int out_size, void* d_ws, size_t ws_size,
                              hipStream_t stream) {
  const float* cover  = (const float*)d_in[0];
  const int*   secret = (const int*)d_in[1];
  float* out = (float*)d_out;
  char*  ws  = (char*)d_ws;

  // ws layout (bytes)
  double*   var      = (double*)(ws);             // 98304*8 = 786432
  unsigned* bins     = (unsigned*)(ws + 786432);  // 8192*4  -> 819200
  unsigned* cand_cnt = (unsigned*)(ws + 819200);  // 4 (pad 16) -> 819216
  int*      desc     = (int*)(ws + 819216);       // 3 ints (pad 32) -> 819248
  ull*      cand     = (ull*)(ws + 819248);       // 2048*8  -> 835632
  int*      packedP  = (int*)(ws + 835632);       // 98304*4 -> 1228848
  int*      bsums    = (int*)(ws + 1228848);      // 96*4    -> 1229232

  k_zero  <<<8,         1024, 0, stream>>>(bins, cand_cnt);
  k_stats <<<NBLK/256,  256,  0, stream>>>(cover, out, var, bins);
  k_gather<<<NBLK/1024, 1024, 0, stream>>>(var, bins, cand_cnt, cand, desc);
  k_tex   <<<NBLK/1024, 1024, 0, stream>>>(var, desc, cand_cnt, cand, packedP, bsums);
  k_embed <<<NBLK/1024, 1024, 0, stream>>>(cover, secret, packedP, bsums, out);
}